// Round 14
// baseline (22622.377 us; speedup 1.0000x reference)
//
#include <hip/hip_runtime.h>

#define H 64
#define G4 256  // 4*H
#define TB 64   // timesteps per proj_h block

typedef _Float16 f16x8 __attribute__((ext_vector_type(8)));
typedef float f32x4 __attribute__((ext_vector_type(4)));
typedef __fp16 p16x2 __attribute__((ext_vector_type(2)));

union I4F { int4 i; f16x8 h; };

__device__ __forceinline__ float sigmoid_f(float x) {
  return 1.f / (1.f + __expf(-x));
}
__device__ __forceinline__ float tanh_f(float x) {
  float e = __expf(2.f * x);
  return 1.f - 2.f / (e + 1.f);
}
__device__ __forceinline__ int pack_f16(float lo, float hi) {
  union { p16x2 h; int i; } u;
  u.h = __builtin_amdgcn_cvt_pkrtz(lo, hi);
  return u.i;
}
// Workgroup barrier draining ONLY lgkmcnt (LDS); globals stay in flight.
__device__ __forceinline__ void wg_barrier() {
  asm volatile("s_waitcnt lgkmcnt(0)\n\ts_barrier" ::: "memory");
}

// Input projection stored cperm-major (pos = u*4 + G): scan lane fetches all
// 4 gate bases of its unit as one float4. Bias folded in.
__global__ __launch_bounds__(G4) void proj_x(const float* __restrict__ x,
                                             const float* __restrict__ W,
                                             const float* __restrict__ b,
                                             float* __restrict__ xw) {
  const int t = blockIdx.x;
  const int j = threadIdx.x;  // original column = G*64 + u
  const int G = j >> 6, u = j & 63;
  xw[(size_t)t * G4 + u * 4 + G] =
      fmaf(x[2 * t], W[j], fmaf(x[2 * t + 1], W[G4 + j], b[j]));
}

// Hidden-state projection GEMM (between scans): xw[t][cperm(j)] = b[j] +
// sum_k hseq[t][k] * W[k][j].  r2-proven structure: W column in registers,
// TB timesteps of h staged in LDS. Massively parallel, runs on all CUs.
__global__ __launch_bounds__(G4) void proj_h(const float* __restrict__ hseq,
                                             const float* __restrict__ W,
                                             const float* __restrict__ b,
                                             float* __restrict__ xw) {
  __shared__ float sh[TB * H];
  const int j = threadIdx.x;  // original column
  const int t0 = blockIdx.x * TB;
  const int pos = ((j & 63) << 2) | (j >> 6);  // cperm = u*4 + G

  float w[H];
#pragma unroll
  for (int k = 0; k < H; ++k) w[k] = W[k * G4 + j];
  const float bj = b[j];

  const float4* src = (const float4*)(hseq + (size_t)t0 * H);
  float4* dst = (float4*)sh;
#pragma unroll
  for (int r = 0; r < (TB * H / 4) / G4; ++r) dst[r * G4 + j] = src[r * G4 + j];
  __syncthreads();

  for (int tt = 0; tt < TB; ++tt) {
    const float4* h4 = (const float4*)(sh + tt * H);
    float a0 = bj, a1 = 0.f, a2 = 0.f, a3 = 0.f;
#pragma unroll
    for (int kk = 0; kk < H / 4; ++kk) {
      float4 hv = h4[kk];
      a0 = fmaf(hv.x, w[4 * kk + 0], a0);
      a1 = fmaf(hv.y, w[4 * kk + 1], a1);
      a2 = fmaf(hv.z, w[4 * kk + 2], a2);
      a3 = fmaf(hv.w, w[4 * kk + 3], a3);
    }
    xw[(size_t)(t0 + tt) * G4 + pos] = (a0 + a1) + (a2 + a3);
  }
}

// Single-layer MFMA LSTM scan: 256 threads = 4 waves (1/SIMD).
// Wave wv owns units 16wv..16wv+15 (cperm cols 64wv..64wv+63).
// z = U^T h via 8 chained mfma_f32_16x16x32_f16 (A = weights in VGPRs,
// B = h replicated over 16 cols from 2 uniform b128 LDS reads).
// r13-hardware-verified mapping: lane (n,kg) after the tsel=n&3 cndmask
// select holds all 4 gates of unit u_own = 16wv+4*(n&3)+kg in regs 0..3.
// Per-thread persistent state: au 32 + nxt 4 + c ≈ 45 VGPRs — inside the
// proven-grantable envelope (~85); waves_per_eu(1,1) removes RA pressure
// entirely (the fused kernels' 130-reg demand was getting sabotaged to 68
// with in-loop remat from L2 — rounds 3-5, 13).
__global__ __attribute__((amdgpu_flat_work_group_size(G4, G4),
                          amdgpu_waves_per_eu(1, 1)))
void lstm_scan(const float* __restrict__ xw,  // [T,256] cperm-major, bias in
               const float* __restrict__ U,   // [64,256] row-major f32
               float* __restrict__ hseq,      // [T,64] f32 out
               int T) {
  __shared__ int4 sh_h[2][8];  // [parity][8 int4 = 64 f16 h]

  const int tid = (int)threadIdx.x;
  const int wv = tid >> 6;
  const int lane = tid & 63;
  const int n = lane & 15;
  const int kg = lane >> 4;
  const int u_own = (wv << 4) | ((n & 3) << 2) | kg;

  // A-fragments (r13-verified construction): tile tau, K-tile kap.
  int4 au[4][2];
#pragma unroll
  for (int tau = 0; tau < 4; ++tau) {
    const int colA = ((n & 3) << 6) | (wv << 4) | (tau << 2) | (n >> 2);
#pragma unroll
    for (int kap = 0; kap < 2; ++kap) {
      const int k0 = kap * 32 + kg * 8;
      au[tau][kap] = make_int4(
          pack_f16(U[(k0 + 0) * G4 + colA], U[(k0 + 1) * G4 + colA]),
          pack_f16(U[(k0 + 2) * G4 + colA], U[(k0 + 3) * G4 + colA]),
          pack_f16(U[(k0 + 4) * G4 + colA], U[(k0 + 5) * G4 + colA]),
          pack_f16(U[(k0 + 6) * G4 + colA], U[(k0 + 7) * G4 + colA]));
      asm volatile("" : "+v"(au[tau][kap].x), "+v"(au[tau][kap].y),
                       "+v"(au[tau][kap].z), "+v"(au[tau][kap].w));
    }
  }

  if (tid < 16) ((int4*)sh_h)[tid] = make_int4(0, 0, 0, 0);
  wg_barrier();

  float c = 0.f;
  float4 nxt = *(const float4*)(xw + u_own * 4);  // xw[0] for own unit

  for (int s = 0; s < T; ++s) {
    const int rbuf = (s - 1) & 1;  // s=0 reads buf1 (zeros = h[-1])
    I4F b0, b1;
    b0.i = sh_h[rbuf][kg];      // h[kg*8 .. +8]   (uniform per kg group)
    b1.i = sh_h[rbuf][4 + kg];  // h[32+kg*8 .. +8]

    f32x4 a0 = {0.f, 0.f, 0.f, 0.f}, a1 = a0, a2 = a0, a3 = a0;
    I4F t00, t01, t10, t11, t20, t21, t30, t31;
    t00.i = au[0][0]; t01.i = au[0][1];
    t10.i = au[1][0]; t11.i = au[1][1];
    t20.i = au[2][0]; t21.i = au[2][1];
    t30.i = au[3][0]; t31.i = au[3][1];
    a0 = __builtin_amdgcn_mfma_f32_16x16x32_f16(t00.h, b0.h, a0, 0, 0, 0);
    a1 = __builtin_amdgcn_mfma_f32_16x16x32_f16(t10.h, b0.h, a1, 0, 0, 0);
    a2 = __builtin_amdgcn_mfma_f32_16x16x32_f16(t20.h, b0.h, a2, 0, 0, 0);
    a3 = __builtin_amdgcn_mfma_f32_16x16x32_f16(t30.h, b0.h, a3, 0, 0, 0);
    a0 = __builtin_amdgcn_mfma_f32_16x16x32_f16(t01.h, b1.h, a0, 0, 0, 0);
    a1 = __builtin_amdgcn_mfma_f32_16x16x32_f16(t11.h, b1.h, a1, 0, 0, 0);
    a2 = __builtin_amdgcn_mfma_f32_16x16x32_f16(t21.h, b1.h, a2, 0, 0, 0);
    a3 = __builtin_amdgcn_mfma_f32_16x16x32_f16(t31.h, b1.h, a3, 0, 0, 0);

    // Select this lane's tile (tsel = n&3): 3 cndmasks per component.
    const bool se = ((n & 1) == 0);
    const bool s01 = ((n & 2) == 0);
    float z0, z1, z2, z3;
    {
      float lo, hi;
      lo = se ? a0[0] : a1[0]; hi = se ? a2[0] : a3[0]; z0 = s01 ? lo : hi;
      lo = se ? a0[1] : a1[1]; hi = se ? a2[1] : a3[1]; z1 = s01 ? lo : hi;
      lo = se ? a0[2] : a1[2]; hi = se ? a2[2] : a3[2]; z2 = s01 ? lo : hi;
      lo = se ? a0[3] : a1[3]; hi = se ? a2[3] : a3[3]; z3 = s01 ? lo : hi;
    }
    z0 += nxt.x; z1 += nxt.y; z2 += nxt.z; z3 += nxt.w;

    const int sn = (s + 1 < T) ? (s + 1) : s;
    nxt = *(const float4*)(xw + (size_t)sn * G4 + u_own * 4);  // prefetch

    const float gi = sigmoid_f(z0);
    const float gf = sigmoid_f(z1);
    const float gg = tanh_f(z2);
    const float go = sigmoid_f(z3);
    c = fmaf(gf, c, gi * gg);
    const float h = go * tanh_f(c);

    if (n < 4) {  // unique writer per unit (n&3==n, n>>2==0)
      ((__fp16*)&sh_h[s & 1][0])[u_own] = (__fp16)h;
      hseq[(size_t)s * H + u_own] = h;  // fire-and-forget f32 for proj/head
    }
    wg_barrier();  // one barrier per step
  }
}

// Dense head: relu(h3@Wd1+bd1) -> relu(@Wd2+bd2) -> @Wl+bl  (all f32)
__global__ __launch_bounds__(64) void head_k(const float* __restrict__ hlast,
                                             const float* __restrict__ Wd1,
                                             const float* __restrict__ bd1,
                                             const float* __restrict__ Wd2,
                                             const float* __restrict__ bd2,
                                             const float* __restrict__ Wl,
                                             const float* __restrict__ bl,
                                             float* __restrict__ out) {
  __shared__ float s_h[H];
  __shared__ float s_a[20];
  __shared__ float s_b[20];
  const int j = threadIdx.x;
  s_h[j] = hlast[j];
  __syncthreads();
  if (j < 20) {
    float acc = bd1[j];
#pragma unroll
    for (int k = 0; k < H; ++k) acc = fmaf(s_h[k], Wd1[k * 20 + j], acc);
    s_a[j] = fmaxf(acc, 0.f);
  }
  __syncthreads();
  if (j < 20) {
    float acc = bd2[j];
#pragma unroll
    for (int k = 0; k < 20; ++k) acc = fmaf(s_a[k], Wd2[k * 20 + j], acc);
    s_b[j] = fmaxf(acc, 0.f);
  }
  __syncthreads();
  if (j < 10) {
    float acc = bl[j];
#pragma unroll
    for (int k = 0; k < 20; ++k) acc = fmaf(s_b[k], Wl[k * 10 + j], acc);
    out[j] = acc;
  }
}

extern "C" void kernel_launch(void* const* d_in, const int* in_sizes, int n_in,
                              void* d_out, int out_size, void* d_ws, size_t ws_size,
                              hipStream_t stream) {
  const float* x   = (const float*)d_in[0];
  const float* W1  = (const float*)d_in[1];
  const float* U1  = (const float*)d_in[2];
  const float* b1  = (const float*)d_in[3];
  const float* W2  = (const float*)d_in[4];
  const float* U2  = (const float*)d_in[5];
  const float* b2  = (const float*)d_in[6];
  const float* W3  = (const float*)d_in[7];
  const float* U3  = (const float*)d_in[8];
  const float* b3  = (const float*)d_in[9];
  const float* Wd1 = (const float*)d_in[10];
  const float* bd1 = (const float*)d_in[11];
  const float* Wd2 = (const float*)d_in[12];
  const float* bd2 = (const float*)d_in[13];
  const float* Wl  = (const float*)d_in[14];
  const float* bl  = (const float*)d_in[15];
  const int T = in_sizes[0] / 2;  // 16384

  // workspace: xw [T,256] | h1 [T,64] | h2 [T,64]  (h3 reuses h1) = 24 MB
  float* xw = (float*)d_ws;
  float* h1 = xw + (size_t)T * G4;
  float* h2 = h1 + (size_t)T * H;

  proj_x<<<T, G4, 0, stream>>>(x, W1, b1, xw);
  lstm_scan<<<1, G4, 0, stream>>>(xw, U1, h1, T);
  proj_h<<<T / TB, G4, 0, stream>>>(h1, W2, b2, xw);
  lstm_scan<<<1, G4, 0, stream>>>(xw, U2, h2, T);
  proj_h<<<T / TB, G4, 0, stream>>>(h2, W3, b3, xw);
  lstm_scan<<<1, G4, 0, stream>>>(xw, U3, h1, T);  // h3 -> h1 buffer
  head_k<<<1, 64, 0, stream>>>(h1 + (size_t)(T - 1) * H, Wd1, bd1, Wd2, bd2,
                               Wl, bl, (float*)d_out);
}

// Round 15
// 11883.656 us; speedup vs baseline: 1.9037x; 1.9037x over previous
//
#include <hip/hip_runtime.h>

#define H 64
#define G4 256   // 4*H
#define CS 512   // timesteps per chunk
#define NC 32    // chunks: T = NC*CS
#define LOG2E 1.44269504088896f

typedef _Float16 f16x8 __attribute__((ext_vector_type(8)));
typedef float f32x4 __attribute__((ext_vector_type(4)));
typedef __fp16 p16x2 __attribute__((ext_vector_type(2)));

union I4F { int4 i; f16x8 h; };

__device__ __forceinline__ int pack_f16s(float lo, float hi, float sc) {
  union { p16x2 h; int i; } u;
  u.h = __builtin_amdgcn_cvt_pkrtz(lo * sc, hi * sc);
  return u.i;
}
// Workgroup barrier draining ONLY lgkmcnt (LDS); globals stay in flight.
__device__ __forceinline__ void wg_barrier() {
  asm volatile("s_waitcnt lgkmcnt(0)\n\ts_barrier" ::: "memory");
}

// Input projection, cperm-major (pos = u*4 + G), bias folded, GATE-SCALED:
// gate g (tanh) pre-activations ×2log2e, sigmoid gates ×(-log2e), so the
// scan's activations are raw exp2-based (no per-step scale multiplies).
__global__ __launch_bounds__(G4) void proj_x(const float* __restrict__ x,
                                             const float* __restrict__ W,
                                             const float* __restrict__ b,
                                             float* __restrict__ xw) {
  const int t = blockIdx.x;
  const int j = threadIdx.x;  // original column = G*64 + u
  const int G = j >> 6, u = j & 63;
  const float sc = (G == 2) ? 2.f * LOG2E : -LOG2E;
  xw[(size_t)t * G4 + u * 4 + G] =
      sc * fmaf(x[2 * t], W[j], fmaf(x[2 * t + 1], W[G4 + j], b[j]));
}

// Chunked-pipeline MFMA LSTM scan. Launch q: block role R scans chunk q-R of
// layer R (if in range) — 3 blocks on 3 DIFFERENT CUs, zero intra-launch
// communication. All cross-layer/cross-chunk data flows through global
// memory across KERNEL LAUNCH BOUNDARIES (full device fences — no XCD
// coherence hazards). Per-block engine = round-14-proven 4-wave MFMA scan
// (VGPR granted 132 at wpe(1,1)): z = U^T h_own (8 MFMA, B from LDS parity
// buffers) [+ W^T h_prev (8 MFMA, B = f16 int4 pair global-prefetched) +
// bias] ; r13-verified fragment/C-D mapping puts all 4 gates of unit
// u_own = 16wv+4(n&3)+kg in one lane's accum regs after a cndmask select.
// Weights/bias/xw gate-scaled => activations are raw exp2+rcp.
__global__ __attribute__((amdgpu_flat_work_group_size(G4, G4),
                          amdgpu_waves_per_eu(1, 1)))
void lstm_scan(int q, const float* __restrict__ xw,
               const float* __restrict__ U1, const float* __restrict__ U2,
               const float* __restrict__ U3, const float* __restrict__ W2,
               const float* __restrict__ W3, const float* __restrict__ b2,
               const float* __restrict__ b3, __fp16* __restrict__ h1s,
               __fp16* __restrict__ h2s, __fp16* __restrict__ hb3,
               float* __restrict__ cst, float* __restrict__ h3out, int T) {
  const int role = (int)blockIdx.x;
  const int chunk = q - role;
  if (chunk < 0 || chunk >= NC) return;
  const int t0 = chunk * CS, t1 = t0 + CS;

  __shared__ int4 sh_h[2][8];  // [parity][8 int4 = 64 f16 own-h]

  const int tid = (int)threadIdx.x;
  const int wv = tid >> 6;
  const int n = tid & 15;
  const int kg = (tid & 63) >> 4;
  const int u_own = (wv << 4) | ((n & 3) << 2) | kg;

  const float* U  = (role == 0) ? U1 : ((role == 1) ? U2 : U3);
  const float* Wp = (role == 0) ? U1 : ((role == 1) ? W2 : W3);  // dummy r0
  const __fp16* hpv = (role == 1) ? h1s : h2s;  // prev-layer h (role>0)
  __fp16* hout = (role == 0) ? h1s : h2s;       // own h out (roles 0,1)

  // Per-lane A-row gate scale: A row m=n has gate n&3.
  const float scl = ((n & 3) == 2) ? 2.f * LOG2E : -LOG2E;

  // A-fragments (r13-verified): tile tau, K-tile kap; scaled at pack.
  I4F au[4][2], aw[4][2];
#pragma unroll
  for (int tau = 0; tau < 4; ++tau) {
    const int colA = ((n & 3) << 6) | (wv << 4) | (tau << 2) | ((tid & 15) >> 2);
#pragma unroll
    for (int kap = 0; kap < 2; ++kap) {
      const int k0 = kap * 32 + kg * 8;
      au[tau][kap].i = make_int4(
          pack_f16s(U[(k0 + 0) * G4 + colA], U[(k0 + 1) * G4 + colA], scl),
          pack_f16s(U[(k0 + 2) * G4 + colA], U[(k0 + 3) * G4 + colA], scl),
          pack_f16s(U[(k0 + 4) * G4 + colA], U[(k0 + 5) * G4 + colA], scl),
          pack_f16s(U[(k0 + 6) * G4 + colA], U[(k0 + 7) * G4 + colA], scl));
      asm volatile("" : "+v"(au[tau][kap].i.x), "+v"(au[tau][kap].i.y),
                       "+v"(au[tau][kap].i.z), "+v"(au[tau][kap].i.w));
      if (role > 0) {
        aw[tau][kap].i = make_int4(
            pack_f16s(Wp[(k0 + 0) * G4 + colA], Wp[(k0 + 1) * G4 + colA], scl),
            pack_f16s(Wp[(k0 + 2) * G4 + colA], Wp[(k0 + 3) * G4 + colA], scl),
            pack_f16s(Wp[(k0 + 4) * G4 + colA], Wp[(k0 + 5) * G4 + colA], scl),
            pack_f16s(Wp[(k0 + 6) * G4 + colA], Wp[(k0 + 7) * G4 + colA], scl));
        asm volatile("" : "+v"(aw[tau][kap].i.x), "+v"(aw[tau][kap].i.y),
                         "+v"(aw[tau][kap].i.z), "+v"(aw[tau][kap].i.w));
      }
    }
  }

  // Gate-scaled bias (roles 1,2): accum reg r carries gate r of u_own.
  float br[4] = {0.f, 0.f, 0.f, 0.f};
  if (role > 0) {
    const float* bb = (role == 1) ? b2 : b3;
#pragma unroll
    for (int r = 0; r < 4; ++r)
      br[r] = bb[r * 64 + u_own] * ((r == 2) ? 2.f * LOG2E : -LOG2E);
  }

  // Cell state restore; own-h parity-buffer init from previous chunk.
  float c = (chunk == 0) ? 0.f : cst[role * 64 + u_own];
  if (tid < 8) {
    int4 v = make_int4(0, 0, 0, 0);
    if (chunk > 0) {
      const int4* src = (role == 0)
              ? (const int4*)(h1s + (size_t)(t0 - 1) * H)
              : (role == 1) ? (const int4*)(h2s + (size_t)(t0 - 1) * H)
                            : (const int4*)hb3;
      v = src[tid];
    }
    sh_h[(t0 - 1) & 1][tid] = v;
  }
  wg_barrier();

  float4 nxt = make_float4(0.f, 0.f, 0.f, 0.f);
  if (role == 0) nxt = *(const float4*)(xw + (size_t)t0 * G4 + u_own * 4);
  I4F hpc0, hpc1;
  if (role > 0) {
    const int4* row = (const int4*)(hpv + (size_t)t0 * H);
    hpc0.i = row[kg]; hpc1.i = row[4 + kg];
  }

  for (int s = t0; s < t1; ++s) {
    I4F b0, b1;
    b0.i = sh_h[(s - 1) & 1][kg];
    b1.i = sh_h[(s - 1) & 1][4 + kg];

    // prefetch next-step h_prev (role>0), consumed next iteration
    I4F hpn0, hpn1;
    if (role > 0) {
      const int tn = (s + 1 < t1) ? (s + 1) : s;
      const int4* rowN = (const int4*)(hpv + (size_t)tn * H);
      hpn0.i = rowN[kg]; hpn1.i = rowN[4 + kg];
    }

    f32x4 a0 = {0.f, 0.f, 0.f, 0.f}, a1 = a0, a2 = a0, a3 = a0;
    a0 = __builtin_amdgcn_mfma_f32_16x16x32_f16(au[0][0].h, b0.h, a0, 0, 0, 0);
    a1 = __builtin_amdgcn_mfma_f32_16x16x32_f16(au[1][0].h, b0.h, a1, 0, 0, 0);
    a2 = __builtin_amdgcn_mfma_f32_16x16x32_f16(au[2][0].h, b0.h, a2, 0, 0, 0);
    a3 = __builtin_amdgcn_mfma_f32_16x16x32_f16(au[3][0].h, b0.h, a3, 0, 0, 0);
    a0 = __builtin_amdgcn_mfma_f32_16x16x32_f16(au[0][1].h, b1.h, a0, 0, 0, 0);
    a1 = __builtin_amdgcn_mfma_f32_16x16x32_f16(au[1][1].h, b1.h, a1, 0, 0, 0);
    a2 = __builtin_amdgcn_mfma_f32_16x16x32_f16(au[2][1].h, b1.h, a2, 0, 0, 0);
    a3 = __builtin_amdgcn_mfma_f32_16x16x32_f16(au[3][1].h, b1.h, a3, 0, 0, 0);
    if (role > 0) {
      a0 = __builtin_amdgcn_mfma_f32_16x16x32_f16(aw[0][0].h, hpc0.h, a0, 0, 0, 0);
      a1 = __builtin_amdgcn_mfma_f32_16x16x32_f16(aw[1][0].h, hpc0.h, a1, 0, 0, 0);
      a2 = __builtin_amdgcn_mfma_f32_16x16x32_f16(aw[2][0].h, hpc0.h, a2, 0, 0, 0);
      a3 = __builtin_amdgcn_mfma_f32_16x16x32_f16(aw[3][0].h, hpc0.h, a3, 0, 0, 0);
      a0 = __builtin_amdgcn_mfma_f32_16x16x32_f16(aw[0][1].h, hpc1.h, a0, 0, 0, 0);
      a1 = __builtin_amdgcn_mfma_f32_16x16x32_f16(aw[1][1].h, hpc1.h, a1, 0, 0, 0);
      a2 = __builtin_amdgcn_mfma_f32_16x16x32_f16(aw[2][1].h, hpc1.h, a2, 0, 0, 0);
      a3 = __builtin_amdgcn_mfma_f32_16x16x32_f16(aw[3][1].h, hpc1.h, a3, 0, 0, 0);
    }

    // Select this lane's tile (tsel = n&3): 3 cndmasks per component.
    const bool se = ((n & 1) == 0);
    const bool s01 = ((n & 2) == 0);
    float z0, z1, z2, z3;
    {
      float lo, hi;
      lo = se ? a0[0] : a1[0]; hi = se ? a2[0] : a3[0]; z0 = s01 ? lo : hi;
      lo = se ? a0[1] : a1[1]; hi = se ? a2[1] : a3[1]; z1 = s01 ? lo : hi;
      lo = se ? a0[2] : a1[2]; hi = se ? a2[2] : a3[2]; z2 = s01 ? lo : hi;
      lo = se ? a0[3] : a1[3]; hi = se ? a2[3] : a3[3]; z3 = s01 ? lo : hi;
    }
    if (role == 0) {
      z0 += nxt.x; z1 += nxt.y; z2 += nxt.z; z3 += nxt.w;
      const int sn = (s + 1 < T) ? (s + 1) : s;
      nxt = *(const float4*)(xw + (size_t)sn * G4 + u_own * 4);  // prefetch
    } else {
      z0 += br[0]; z1 += br[1]; z2 += br[2]; z3 += br[3];
    }

    // Scaled activations: sigmoid = rcp(1+2^z'), tanh = 1-2*rcp(1+2^z').
    const float gi = __builtin_amdgcn_rcpf(1.f + exp2f(z0));
    const float gf = __builtin_amdgcn_rcpf(1.f + exp2f(z1));
    const float gg = fmaf(-2.f, __builtin_amdgcn_rcpf(1.f + exp2f(z2)), 1.f);
    const float go = __builtin_amdgcn_rcpf(1.f + exp2f(z3));
    c = fmaf(gf, c, gi * gg);
    const float th =
        fmaf(-2.f, __builtin_amdgcn_rcpf(1.f + exp2f(c * (2.f * LOG2E))), 1.f);
    const float h = go * th;

    if (n < 4) {  // unique writer per unit
      ((__fp16*)&sh_h[s & 1][0])[u_own] = (__fp16)h;
      if (role < 2) {
        hout[(size_t)s * H + u_own] = (__fp16)h;  // fire-and-forget
      } else {
        if (s == t1 - 1) hb3[u_own] = (__fp16)h;   // boundary h for restore
        if (s == T - 1) h3out[u_own] = h;          // f32 for the head
      }
      if (s == t1 - 1) cst[role * 64 + u_own] = c;  // cell state save
    }
    if (role > 0) { hpc0 = hpn0; hpc1 = hpn1; }
    wg_barrier();  // one barrier per step
  }
}

// Dense head: relu(h3@Wd1+bd1) -> relu(@Wd2+bd2) -> @Wl+bl  (all f32)
__global__ __launch_bounds__(64) void head_k(const float* __restrict__ hlast,
                                             const float* __restrict__ Wd1,
                                             const float* __restrict__ bd1,
                                             const float* __restrict__ Wd2,
                                             const float* __restrict__ bd2,
                                             const float* __restrict__ Wl,
                                             const float* __restrict__ bl,
                                             float* __restrict__ out) {
  __shared__ float s_h[H];
  __shared__ float s_a[20];
  __shared__ float s_b[20];
  const int j = threadIdx.x;
  s_h[j] = hlast[j];
  __syncthreads();
  if (j < 20) {
    float acc = bd1[j];
#pragma unroll
    for (int k = 0; k < H; ++k) acc = fmaf(s_h[k], Wd1[k * 20 + j], acc);
    s_a[j] = fmaxf(acc, 0.f);
  }
  __syncthreads();
  if (j < 20) {
    float acc = bd2[j];
#pragma unroll
    for (int k = 0; k < 20; ++k) acc = fmaf(s_a[k], Wd2[k * 20 + j], acc);
    s_b[j] = fmaxf(acc, 0.f);
  }
  __syncthreads();
  if (j < 10) {
    float acc = bl[j];
#pragma unroll
    for (int k = 0; k < 20; ++k) acc = fmaf(s_b[k], Wl[k * 10 + j], acc);
    out[j] = acc;
  }
}

extern "C" void kernel_launch(void* const* d_in, const int* in_sizes, int n_in,
                              void* d_out, int out_size, void* d_ws, size_t ws_size,
                              hipStream_t stream) {
  const float* x   = (const float*)d_in[0];
  const float* W1  = (const float*)d_in[1];
  const float* U1  = (const float*)d_in[2];
  const float* b1  = (const float*)d_in[3];
  const float* W2  = (const float*)d_in[4];
  const float* U2  = (const float*)d_in[5];
  const float* b2  = (const float*)d_in[6];
  const float* W3  = (const float*)d_in[7];
  const float* U3  = (const float*)d_in[8];
  const float* b3  = (const float*)d_in[9];
  const float* Wd1 = (const float*)d_in[10];
  const float* bd1 = (const float*)d_in[11];
  const float* Wd2 = (const float*)d_in[12];
  const float* bd2 = (const float*)d_in[13];
  const float* Wl  = (const float*)d_in[14];
  const float* bl  = (const float*)d_in[15];
  const int T = in_sizes[0] / 2;  // 16384 = NC*CS

  // workspace: xw [T,256] f32 | h1s [T,64] f16 | h2s [T,64] f16 |
  //            hb3 [64] f16 | cst [192] f32 | h3out [64] f32
  float* xw = (float*)d_ws;
  __fp16* h1s = (__fp16*)(xw + (size_t)T * G4);
  __fp16* h2s = h1s + (size_t)T * H;
  __fp16* hb3 = h2s + (size_t)T * H;
  float* cst = (float*)(hb3 + H);
  float* h3out = cst + 192;

  proj_x<<<T, G4, 0, stream>>>(x, W1, b1, xw);
  for (int q = 0; q < NC + 2; ++q) {
    lstm_scan<<<3, G4, 0, stream>>>(q, xw, U1, U2, U3, W2, W3, b2, b3, h1s,
                                    h2s, hb3, cst, h3out, T);
  }
  head_k<<<1, 64, 0, stream>>>(h3out, Wd1, bd1, Wd2, bd2, Wl, bl,
                               (float*)d_out);
}

// Round 16
// 8282.516 us; speedup vs baseline: 2.7313x; 1.4348x over previous
//
#include <hip/hip_runtime.h>

#define H 64
#define G4 256   // 4*H
#define CS 512   // timesteps per chunk
#define NC 32    // chunks: T = NC*CS
#define PB 16    // proj blocks per layer-projection
#define TPB (CS / PB)  // 32 timesteps per proj block
#define LOG2E 1.44269504088896f

typedef _Float16 f16x8 __attribute__((ext_vector_type(8)));
typedef float f32x4 __attribute__((ext_vector_type(4)));
typedef __fp16 p16x2 __attribute__((ext_vector_type(2)));

union I4F { int4 i; f16x8 h; };

__device__ __forceinline__ int pack_f16s(float lo, float hi, float sc) {
  union { p16x2 h; int i; } u;
  u.h = __builtin_amdgcn_cvt_pkrtz(lo * sc, hi * sc);
  return u.i;
}
// Workgroup barrier draining ONLY lgkmcnt (LDS); globals stay in flight.
__device__ __forceinline__ void wg_barrier() {
  asm volatile("s_waitcnt lgkmcnt(0)\n\ts_barrier" ::: "memory");
}

// Input projection, cperm-major (pos = u*4 + G), bias folded, gate-scaled
// (tanh gate ×2log2e, sigmoid gates ×-log2e -> scan uses raw exp2+rcp).
__global__ __launch_bounds__(G4) void proj_x(const float* __restrict__ x,
                                             const float* __restrict__ W,
                                             const float* __restrict__ b,
                                             float* __restrict__ xw) {
  const int t = blockIdx.x;
  const int j = threadIdx.x;  // original column = G*64 + u
  const int G = j >> 6, u = j & 63;
  const float sc = (G == 2) ? 2.f * LOG2E : -LOG2E;
  xw[(size_t)t * G4 + u * 4 + G] =
      sc * fmaf(x[2 * t], W[j], fmaf(x[2 * t + 1], W[G4 + j], b[j]));
}

// One pipeline step (launch q). All dependencies cross LAUNCH boundaries
// (full fences) — zero intra-launch communication.
//   block 0:  scan L0, chunk q     (xw from proj_x; h1s out)
//   block 1:  scan L1, chunk q-2   (xw2s ring in; h2s out)
//   block 2:  scan L2, chunk q-4   (xw3s ring in; hb3/cst/h3out)
//   blocks 3..18:  proj2 chunk q-1: xw2s = scl*(W2^T h1 + b2)
//   blocks 19..34: proj3 chunk q-3: xw3s = scl*(W3^T h2 + b3)
// Scan engine = round-14-proven 4-wave pure-U MFMA scan (461 ns/step,
// VGPR granted at wpe(1,1)): 8 mfma_16x16x32_f16, B = own-h f16 from LDS
// parity buffers, r13-verified mapping -> all 4 gates of unit
// u_own = 16wv+4(n&3)+kg in one lane after a 12-op cndmask select.
// The W-matvec is OFF the critical path (proj blocks, parallel CUs).
// Ring-2 xw buffers: writer chunk parity != reader chunk parity; the slot
// being overwritten was consumed 2 launches earlier.
__global__ __attribute__((amdgpu_flat_work_group_size(G4, G4),
                          amdgpu_waves_per_eu(1, 1)))
void pipe_step(int q, const float* __restrict__ xw1,
               const float* __restrict__ U1, const float* __restrict__ U2,
               const float* __restrict__ U3, const float* __restrict__ W2,
               const float* __restrict__ W3, const float* __restrict__ b2,
               const float* __restrict__ b3, __fp16* __restrict__ h1s,
               __fp16* __restrict__ h2s, __fp16* __restrict__ hb3,
               float* __restrict__ xw2s, float* __restrict__ xw3s,
               float* __restrict__ cst, float* __restrict__ h3out, int T) {
  const int bid = (int)blockIdx.x;
  const int tid = (int)threadIdx.x;

  // ================= proj blocks =================
  if (bid >= 3) {
    const int p = bid - 3;
    const int lay = p / PB;            // 0: L1 input, 1: L2 input
    const int pb = p % PB;
    const int chunk = q - 1 - 2 * lay;  // q-1 or q-3
    if (chunk < 0 || chunk >= NC) return;
    const __fp16* hsrc = lay ? h2s : h1s;
    const float* Wm = lay ? W3 : W2;
    const float* bb = lay ? b3 : b2;
    float* dst = (lay ? xw3s : xw2s) + (size_t)(chunk & 1) * CS * G4;
    const int tl0 = pb * TPB;  // local timestep base within chunk

    __shared__ float sh[TPB * H];  // staged h, f32 (8 KB)
    {  // stage TPB*64 f16 = 4096 B = 256 int4: one int4 per thread, cvt f32
      union { int4 i; __fp16 hh[8]; } uu;
      uu.i = ((const int4*)(hsrc + (size_t)(chunk * CS + tl0) * H))[tid];
      float4 lo = make_float4(uu.hh[0], uu.hh[1], uu.hh[2], uu.hh[3]);
      float4 hi = make_float4(uu.hh[4], uu.hh[5], uu.hh[6], uu.hh[7]);
      ((float4*)sh)[2 * tid] = lo;
      ((float4*)sh)[2 * tid + 1] = hi;
    }
    __syncthreads();

    const int j = tid;  // original column
    const int G = j >> 6, u = j & 63;
    const int pos = (u << 2) | G;  // cperm
    const float scl = (G == 2) ? 2.f * LOG2E : -LOG2E;
    float w[H];
#pragma unroll
    for (int k = 0; k < H; ++k) w[k] = Wm[k * G4 + j];
    const float bj = bb[j];

    for (int tt = 0; tt < TPB; ++tt) {
      const float4* h4 = (const float4*)(sh + tt * H);
      float a0 = bj, a1 = 0.f, a2 = 0.f, a3 = 0.f;
#pragma unroll
      for (int kk = 0; kk < H / 4; ++kk) {
        float4 hv = h4[kk];
        a0 = fmaf(hv.x, w[4 * kk + 0], a0);
        a1 = fmaf(hv.y, w[4 * kk + 1], a1);
        a2 = fmaf(hv.z, w[4 * kk + 2], a2);
        a3 = fmaf(hv.w, w[4 * kk + 3], a3);
      }
      dst[(size_t)(tl0 + tt) * G4 + pos] = scl * ((a0 + a1) + (a2 + a3));
    }
    return;
  }

  // ================= scan blocks =================
  const int role = bid;
  const int chunk = q - 2 * role;
  if (chunk < 0 || chunk >= NC) return;
  const int t0 = chunk * CS, t1 = t0 + CS;

  __shared__ int4 sh_h[2][8];  // [parity][8 int4 = 64 f16 own-h]

  const int wv = tid >> 6;
  const int n = tid & 15;
  const int kg = (tid & 63) >> 4;
  const int u_own = (wv << 4) | ((n & 3) << 2) | kg;

  const float* U = (role == 0) ? U1 : ((role == 1) ? U2 : U3);
  const float scl = ((n & 3) == 2) ? 2.f * LOG2E : -LOG2E;

  // A-fragments (r13-verified), gate-scaled at pack.
  I4F au[4][2];
#pragma unroll
  for (int tau = 0; tau < 4; ++tau) {
    const int colA = ((n & 3) << 6) | (wv << 4) | (tau << 2) | (n >> 2);
#pragma unroll
    for (int kap = 0; kap < 2; ++kap) {
      const int k0 = kap * 32 + kg * 8;
      au[tau][kap].i = make_int4(
          pack_f16s(U[(k0 + 0) * G4 + colA], U[(k0 + 1) * G4 + colA], scl),
          pack_f16s(U[(k0 + 2) * G4 + colA], U[(k0 + 3) * G4 + colA], scl),
          pack_f16s(U[(k0 + 4) * G4 + colA], U[(k0 + 5) * G4 + colA], scl),
          pack_f16s(U[(k0 + 6) * G4 + colA], U[(k0 + 7) * G4 + colA], scl));
      asm volatile("" : "+v"(au[tau][kap].i.x), "+v"(au[tau][kap].i.y),
                       "+v"(au[tau][kap].i.z), "+v"(au[tau][kap].i.w));
    }
  }

  // xw stream base (bias+scale folded for ALL roles), local index tt.
  const float* xbase =
      (role == 0) ? (xw1 + (size_t)t0 * G4)
                  : ((role == 1) ? xw2s : xw3s) + (size_t)(chunk & 1) * CS * G4;
  __fp16* hout = (role == 0) ? h1s : h2s;  // roles 0,1 publish h sequence

  // Cell state + own-h parity init (all cross-launch data).
  float c = (chunk == 0) ? 0.f : cst[role * 64 + u_own];
  if (tid < 8) {
    int4 v = make_int4(0, 0, 0, 0);
    if (chunk > 0) {
      const int4* src = (role == 0)
              ? (const int4*)(h1s + (size_t)(t0 - 1) * H)
              : (role == 1) ? (const int4*)(h2s + (size_t)(t0 - 1) * H)
                            : (const int4*)hb3;
      v = src[tid];
    }
    sh_h[(t0 - 1) & 1][tid] = v;
  }
  wg_barrier();

  float4 nxt = *(const float4*)(xbase + (size_t)0 * G4 + u_own * 4);

  for (int tt = 0; tt < CS; ++tt) {
    const int s = t0 + tt;
    I4F b0, b1;
    b0.i = sh_h[(s - 1) & 1][kg];
    b1.i = sh_h[(s - 1) & 1][4 + kg];

    f32x4 a0 = {0.f, 0.f, 0.f, 0.f}, a1 = a0, a2 = a0, a3 = a0;
    a0 = __builtin_amdgcn_mfma_f32_16x16x32_f16(au[0][0].h, b0.h, a0, 0, 0, 0);
    a1 = __builtin_amdgcn_mfma_f32_16x16x32_f16(au[1][0].h, b0.h, a1, 0, 0, 0);
    a2 = __builtin_amdgcn_mfma_f32_16x16x32_f16(au[2][0].h, b0.h, a2, 0, 0, 0);
    a3 = __builtin_amdgcn_mfma_f32_16x16x32_f16(au[3][0].h, b0.h, a3, 0, 0, 0);
    a0 = __builtin_amdgcn_mfma_f32_16x16x32_f16(au[0][1].h, b1.h, a0, 0, 0, 0);
    a1 = __builtin_amdgcn_mfma_f32_16x16x32_f16(au[1][1].h, b1.h, a1, 0, 0, 0);
    a2 = __builtin_amdgcn_mfma_f32_16x16x32_f16(au[2][1].h, b1.h, a2, 0, 0, 0);
    a3 = __builtin_amdgcn_mfma_f32_16x16x32_f16(au[3][1].h, b1.h, a3, 0, 0, 0);

    // Tile select (tsel = n&3): 3 cndmasks per component.
    const bool se = ((n & 1) == 0);
    const bool s01 = ((n & 2) == 0);
    float z0, z1, z2, z3;
    {
      float lo, hi;
      lo = se ? a0[0] : a1[0]; hi = se ? a2[0] : a3[0]; z0 = s01 ? lo : hi;
      lo = se ? a0[1] : a1[1]; hi = se ? a2[1] : a3[1]; z1 = s01 ? lo : hi;
      lo = se ? a0[2] : a1[2]; hi = se ? a2[2] : a3[2]; z2 = s01 ? lo : hi;
      lo = se ? a0[3] : a1[3]; hi = se ? a2[3] : a3[3]; z3 = s01 ? lo : hi;
    }
    z0 += nxt.x; z1 += nxt.y; z2 += nxt.z; z3 += nxt.w;

    const int tn = (tt + 1 < CS) ? (tt + 1) : tt;
    nxt = *(const float4*)(xbase + (size_t)tn * G4 + u_own * 4);  // prefetch

    // Scaled activations: sigmoid = rcp(1+2^z'), tanh = 1-2*rcp(1+2^z').
    const float gi = __builtin_amdgcn_rcpf(1.f + exp2f(z0));
    const float gf = __builtin_amdgcn_rcpf(1.f + exp2f(z1));
    const float gg = fmaf(-2.f, __builtin_amdgcn_rcpf(1.f + exp2f(z2)), 1.f);
    const float go = __builtin_amdgcn_rcpf(1.f + exp2f(z3));
    c = fmaf(gf, c, gi * gg);
    const float th =
        fmaf(-2.f, __builtin_amdgcn_rcpf(1.f + exp2f(c * (2.f * LOG2E))), 1.f);
    const float h = go * th;

    if (n < 4) {  // unique writer per unit
      ((__fp16*)&sh_h[s & 1][0])[u_own] = (__fp16)h;
      if (role < 2) {
        hout[(size_t)s * H + u_own] = (__fp16)h;  // fire-and-forget
      } else {
        if (tt == CS - 1) hb3[u_own] = (__fp16)h;
        if (s == T - 1) h3out[u_own] = h;
      }
      if (tt == CS - 1) cst[role * 64 + u_own] = c;
    }
    wg_barrier();  // one barrier per step
  }
}

// Dense head: relu(h3@Wd1+bd1) -> relu(@Wd2+bd2) -> @Wl+bl  (all f32)
__global__ __launch_bounds__(64) void head_k(const float* __restrict__ hlast,
                                             const float* __restrict__ Wd1,
                                             const float* __restrict__ bd1,
                                             const float* __restrict__ Wd2,
                                             const float* __restrict__ bd2,
                                             const float* __restrict__ Wl,
                                             const float* __restrict__ bl,
                                             float* __restrict__ out) {
  __shared__ float s_h[H];
  __shared__ float s_a[20];
  __shared__ float s_b[20];
  const int j = threadIdx.x;
  s_h[j] = hlast[j];
  __syncthreads();
  if (j < 20) {
    float acc = bd1[j];
#pragma unroll
    for (int k = 0; k < H; ++k) acc = fmaf(s_h[k], Wd1[k * 20 + j], acc);
    s_a[j] = fmaxf(acc, 0.f);
  }
  __syncthreads();
  if (j < 20) {
    float acc = bd2[j];
#pragma unroll
    for (int k = 0; k < 20; ++k) acc = fmaf(s_a[k], Wd2[k * 20 + j], acc);
    s_b[j] = fmaxf(acc, 0.f);
  }
  __syncthreads();
  if (j < 10) {
    float acc = bl[j];
#pragma unroll
    for (int k = 0; k < 20; ++k) acc = fmaf(s_b[k], Wl[k * 10 + j], acc);
    out[j] = acc;
  }
}

extern "C" void kernel_launch(void* const* d_in, const int* in_sizes, int n_in,
                              void* d_out, int out_size, void* d_ws, size_t ws_size,
                              hipStream_t stream) {
  const float* x   = (const float*)d_in[0];
  const float* W1  = (const float*)d_in[1];
  const float* U1  = (const float*)d_in[2];
  const float* b1  = (const float*)d_in[3];
  const float* W2  = (const float*)d_in[4];
  const float* U2  = (const float*)d_in[5];
  const float* b2  = (const float*)d_in[6];
  const float* W3  = (const float*)d_in[7];
  const float* U3  = (const float*)d_in[8];
  const float* b3  = (const float*)d_in[9];
  const float* Wd1 = (const float*)d_in[10];
  const float* bd1 = (const float*)d_in[11];
  const float* Wd2 = (const float*)d_in[12];
  const float* bd2 = (const float*)d_in[13];
  const float* Wl  = (const float*)d_in[14];
  const float* bl  = (const float*)d_in[15];
  const int T = in_sizes[0] / 2;  // 16384 = NC*CS

  // workspace: xw1 [T,256] f32 (16.8MB) | h1s,h2s [T,64] f16 (2.1MB ea) |
  // xw2s,xw3s ring2 [2*CS,256] f32 (1.05MB ea) | hb3 | cst | h3out  ~23.2MB
  float* xw1 = (float*)d_ws;
  __fp16* h1s = (__fp16*)(xw1 + (size_t)T * G4);
  __fp16* h2s = h1s + (size_t)T * H;
  float* xw2s = (float*)(h2s + (size_t)T * H);
  float* xw3s = xw2s + 2 * CS * G4;
  __fp16* hb3 = (__fp16*)(xw3s + 2 * CS * G4);
  float* cst = (float*)(hb3 + H);
  float* h3out = cst + 192;

  proj_x<<<T, G4, 0, stream>>>(x, W1, b1, xw1);
  for (int q = 0; q < NC + 4; ++q) {
    pipe_step<<<3 + 2 * PB, G4, 0, stream>>>(q, xw1, U1, U2, U3, W2, W3, b2,
                                             b3, h1s, h2s, hb3, xw2s, xw3s,
                                             cst, h3out, T);
  }
  head_k<<<1, 64, 0, stream>>>(h3out, Wd1, bd1, Wd2, bd2, Wl, bl,
                               (float*)d_out);
}